// Round 6
// baseline (307.345 us; speedup 1.0000x reference)
//
#include <hip/hip_runtime.h>
#include <hip/hip_bf16.h>

#define N_NODES 200000
#define N_EDGES 640000
#define D_NODE 128
#define D_EDGE 32
#define HIDDEN 128
#define KTOT 288          // 128 (x) + 128 (Sx) + 32 (Sea)

using bf16x8  = __attribute__((ext_vector_type(8))) short;
using f32x4   = __attribute__((ext_vector_type(4))) float;
using short4v = __attribute__((ext_vector_type(4))) short;

__device__ __forceinline__ short f2b(float f) {
  return __builtin_bit_cast(short, __float2bfloat16(f));
}
__device__ __forceinline__ float b2f(short s) {
  unsigned u = ((unsigned)(unsigned short)s) << 16;
  return __builtin_bit_cast(float, u);
}

// ===========================================================================
// prep_x (x -> bf16 xb) fused with hist (slot = atomicAdd(cnt[dst]))
//   blocks [0, 12500)  : prep_x, i = b*256+tid over N_NODES*16 octs
//   blocks [12500, 15000): hist, e = (b-12500)*256+tid
// ===========================================================================
#define PREP_NB 12500   // N_NODES*16/256
#define HIST_NB 2500    // N_EDGES/256

__global__ __launch_bounds__(256) void k_prep(
    const float* __restrict__ x, short* __restrict__ xb,
    const int* __restrict__ ei, int* cnt, int* slot)
{
  const int b = blockIdx.x;
  if (b < PREP_NB) {
    const int i = b * 256 + threadIdx.x;
    const int node = i >> 4;
    const int oct  = (i & 15) << 3;
    const float4 v0 = *(const float4*)&x[(size_t)node * D_NODE + oct];
    const float4 v1 = *(const float4*)&x[(size_t)node * D_NODE + oct + 4];
    bf16x8 o = { f2b(v0.x), f2b(v0.y), f2b(v0.z), f2b(v0.w),
                 f2b(v1.x), f2b(v1.y), f2b(v1.z), f2b(v1.w) };
    *(bf16x8*)&xb[(size_t)node * D_NODE + oct] = o;
  } else {
    const int e = (b - PREP_NB) * 256 + threadIdx.x;
    if (e < N_EDGES) slot[e] = atomicAdd(&cnt[ei[N_EDGES + e]], 1);
  }
}

__global__ __launch_bounds__(128) void k_prep_wc(const float* __restrict__ W1,
                                                 const float* __restrict__ b1,
                                                 const float* __restrict__ W2,
                                                 short* __restrict__ WcT,
                                                 float* __restrict__ bc) {
  const int b = blockIdx.x;     // 0..288
  const int c = threadIdx.x;    // 0..127
  if (b < 128) {
    WcT[c * KTOT + b] = f2b(W2[b * 128 + c]);          // W2 top rows (x part)
  } else if (b < KTOT) {
    const int i = b - 128;                             // W1 row i
    float acc = 0.f;
    #pragma unroll 8
    for (int q = 0; q < 128; ++q)
      acc += W1[i * 128 + q] * W2[(128 + q) * 128 + c];
    WcT[c * KTOT + b] = f2b(acc);
  } else {
    float acc = 0.f;
    #pragma unroll 8
    for (int q = 0; q < 128; ++q)
      acc += b1[q] * W2[(128 + q) * 128 + c];
    bc[c] = acc;
  }
}

// ===========================================================================
// CSR scan chain + place
// ===========================================================================
#define SCAN_NB 196  // ceil(200000/1024)

__global__ __launch_bounds__(256) void k_scan_a(const int* __restrict__ cnt,
                                                int* bsum) {
  __shared__ int sh[256];
  const int b = blockIdx.x, t = threadIdx.x;
  const int base = b * 1024 + t * 4;
  int s = 0;
  #pragma unroll
  for (int k = 0; k < 4; ++k) {
    const int idx = base + k;
    s += (idx < N_NODES) ? cnt[idx] : 0;
  }
  sh[t] = s; __syncthreads();
  for (int o = 128; o > 0; o >>= 1) {
    if (t < o) sh[t] += sh[t + o];
    __syncthreads();
  }
  if (t == 0) bsum[b] = sh[0];
}

__global__ __launch_bounds__(256) void k_scan_b(const int* __restrict__ bsum,
                                                int* bpre) {
  __shared__ int sh[256];
  const int t = threadIdx.x;
  const int v0 = (t < SCAN_NB) ? bsum[t] : 0;
  sh[t] = v0; __syncthreads();
  for (int o = 1; o < 256; o <<= 1) {
    const int tv = (t >= o) ? sh[t - o] : 0;
    __syncthreads();
    sh[t] += tv;
    __syncthreads();
  }
  bpre[t] = sh[t] - v0;  // exclusive
}

__global__ __launch_bounds__(256) void k_scan_c(const int* __restrict__ cnt,
                                                const int* __restrict__ bpre,
                                                int* offv) {
  __shared__ int sh[256];
  const int b = blockIdx.x, t = threadIdx.x;
  const int base = b * 1024 + t * 4;
  int v[4], p[4], s = 0;
  #pragma unroll
  for (int k = 0; k < 4; ++k) {
    const int idx = base + k;
    v[k] = (idx < N_NODES) ? cnt[idx] : 0;
    p[k] = s; s += v[k];
  }
  sh[t] = s; __syncthreads();
  const int tot = s;
  for (int o = 1; o < 256; o <<= 1) {
    const int tv = (t >= o) ? sh[t - o] : 0;
    __syncthreads();
    sh[t] += tv;
    __syncthreads();
  }
  const int gb = bpre[b] + (sh[t] - tot);
  #pragma unroll
  for (int k = 0; k < 4; ++k) {
    const int idx = base + k;
    if (idx < N_NODES) offv[idx] = gb + p[k];
  }
}

__global__ __launch_bounds__(256) void k_place2(const int* __restrict__ ei,
                                                const int* __restrict__ offv,
                                                const int* __restrict__ slot,
                                                int* perm, int* rows) {
  const int e = blockIdx.x * 256 + threadIdx.x;
  if (e < N_EDGES) {
    const int j = offv[ei[N_EDGES + e]] + slot[e];
    perm[j] = e;
    rows[j] = ei[e];   // source row, pre-resolved
  }
}

// ===========================================================================
// Fused gather + GEMM.  Block owns 32 nodes:
//   phase 0 staging: LDS A[32][288] = [ xb | sum_x(gather) | sum_ea(gather) ]
//   then out = A @ Wc + cnt*bc + b2, K=288 in 3x96 phases (B 128x96 per phase)
//   LDS 45.6 KB -> 3 blocks/CU; gather of one block overlaps MFMA of others.
// ===========================================================================
#define BM  32
#define LDA 296   // 592B row stride: step 20 banks/row -> 2-way alias (free)
#define LDB 104   // 208B row stride: same class, 2-way (free)

__global__ __launch_bounds__(256, 3) void k_outF(
    const short* __restrict__ xb, const float* __restrict__ ea,
    const int* __restrict__ offv, const int* __restrict__ cnt,
    const int* __restrict__ rows, const int* __restrict__ perm,
    const short* __restrict__ WcT, const float* __restrict__ bc,
    const float* __restrict__ b2, float* __restrict__ out)
{
  __shared__ short sA[BM * LDA];     // 18944 B
  __shared__ short sB[128 * LDB];    // 26624 B
  const int tid = threadIdx.x;
  const int n0  = blockIdx.x * BM;   // grid 6250, exact

  // ---- stage A: x copy (512 tasks) + Sx gather (512) + Sea gather (256) ----
  for (int i = tid; i < 1280; i += 256) {
    if (i < 512) {
      const int m = i >> 4, oct = (i & 15) << 3;
      *(bf16x8*)&sA[m * LDA + oct] =
          *(const bf16x8*)&xb[(size_t)(n0 + m) * D_NODE + oct];
    } else if (i < 1024) {
      const int t = i - 512;
      const int m = t >> 4, oct = (t & 15) << 3;
      const int s0 = offv[n0 + m];
      const int s1 = s0 + cnt[n0 + m];
      float a[8] = {};
      for (int j = s0; j < s1; ++j) {
        const bf16x8 v = *(const bf16x8*)&xb[(size_t)rows[j] * D_NODE + oct];
        #pragma unroll
        for (int k = 0; k < 8; ++k) a[k] += b2f(v[k]);
      }
      bf16x8 o;
      #pragma unroll
      for (int k = 0; k < 8; ++k) o[k] = f2b(a[k]);
      *(bf16x8*)&sA[m * LDA + 128 + oct] = o;
    } else {
      const int t = i - 1024;
      const int m = t >> 3, q = (t & 7) << 2;
      const int s0 = offv[n0 + m];
      const int s1 = s0 + cnt[n0 + m];
      float a0 = 0.f, a1 = 0.f, a2 = 0.f, a3 = 0.f;
      for (int j = s0; j < s1; ++j) {
        const float4 v = *(const float4*)&ea[(size_t)perm[j] * D_EDGE + q];
        a0 += v.x; a1 += v.y; a2 += v.z; a3 += v.w;
      }
      short4v o = { f2b(a0), f2b(a1), f2b(a2), f2b(a3) };
      *(short4v*)&sA[m * LDA + 256 + q] = o;
    }
  }
  // ---- stage B phase 0 ----
  for (int i = tid; i < 1536; i += 256) {
    const int n = i / 12, ck = (i % 12) << 3;
    *(bf16x8*)&sB[n * LDB + ck] = *(const bf16x8*)&WcT[n * KTOT + ck];
  }
  __syncthreads();

  const int lane = tid & 63;
  const int wid  = tid >> 6;
  const int wm = wid >> 1, wn = wid & 1;    // 2x2 waves, 16x64 out each
  const int lrow = lane & 15;
  const int lk   = (lane >> 4) << 3;

  f32x4 acc[4] = {};
  #pragma unroll
  for (int p = 0; p < 3; ++p) {
    #pragma unroll
    for (int kt = 0; kt < 3; ++kt) {
      const int ks = kt * 32 + lk;
      const bf16x8 af = *(const bf16x8*)&sA[(wm * 16 + lrow) * LDA + p * 96 + ks];
      bf16x8 bfr[4];
      #pragma unroll
      for (int j = 0; j < 4; ++j)
        bfr[j] = *(const bf16x8*)&sB[(wn * 64 + j * 16 + lrow) * LDB + ks];
      #pragma unroll
      for (int j = 0; j < 4; ++j)
        acc[j] = __builtin_amdgcn_mfma_f32_16x16x32_bf16(af, bfr[j], acc[j], 0, 0, 0);
    }
    __syncthreads();               // all reads of sB(p) done
    if (p < 2) {
      for (int i = tid; i < 1536; i += 256) {
        const int n = i / 12, ck = (i % 12) << 3;
        *(bf16x8*)&sB[n * LDB + ck] =
            *(const bf16x8*)&WcT[n * KTOT + (p + 1) * 96 + ck];
      }
      __syncthreads();
    }
  }

  // ---- epilogue: acc + cnt*bc + b2 -> LDS f32 [32][128] -> coalesced stores
  float* lf = (float*)sA;          // 16384 B <= 18944 B
  const int rb = wm * 16 + ((lane >> 4) << 2);
  const int cb = wn * 64 + lrow;
  float bcv[4], b2v[4];
  #pragma unroll
  for (int j = 0; j < 4; ++j) {
    bcv[j] = bc[cb + j * 16];
    b2v[j] = b2[cb + j * 16];
  }
  #pragma unroll
  for (int r = 0; r < 4; ++r) {
    const int row = rb + r;
    const float cf = (float)cnt[n0 + row];
    #pragma unroll
    for (int j = 0; j < 4; ++j)
      lf[row * 128 + cb + j * 16] = acc[j][r] + cf * bcv[j] + b2v[j];
  }
  __syncthreads();
  #pragma unroll
  for (int u = 0; u < 4; ++u) {
    const int idx = tid + u * 256;           // 1024 float4s
    const int row = idx >> 5, f4 = (idx & 31) << 2;
    *(float4*)&out[(size_t)(n0 + row) * HIDDEN + f4] = *(const float4*)&lf[row * 128 + f4];
  }
}

extern "C" void kernel_launch(void* const* d_in, const int* in_sizes, int n_in,
                              void* d_out, int out_size, void* d_ws, size_t ws_size,
                              hipStream_t stream) {
  const float* x  = (const float*)d_in[0];
  const int*   ei = (const int*)d_in[1];
  const float* ea = (const float*)d_in[2];
  const float* W1 = (const float*)d_in[5];
  const float* b1 = (const float*)d_in[6];
  const float* W2 = (const float*)d_in[7];
  const float* b2 = (const float*)d_in[8];
  float* out = (float*)d_out;

  const size_t XB_B   = (size_t)N_NODES * D_NODE * 2;  // 51,200,000
  const size_t WCT_B  = 128 * KTOT * 2;                //      73,728
  const size_t BC_B   = 512;
  const size_t CNT_B  = (size_t)N_NODES * 4;           //     800,000
  const size_t SLOT_B = (size_t)N_EDGES * 4;           //   2,560,000

  const size_t o_xb   = 0;
  const size_t o_wct  = o_xb + XB_B;
  const size_t o_bc   = o_wct + WCT_B;
  const size_t o_cnt  = o_bc + BC_B;
  const size_t o_off  = o_cnt + CNT_B;
  const size_t o_slot = o_off + CNT_B;
  const size_t o_perm = o_slot + SLOT_B;
  const size_t o_rows = o_perm + SLOT_B;
  const size_t o_bsum = o_rows + SLOT_B;
  const size_t o_bpre = o_bsum + 1024;
  // total ~63 MB (round-5 plan used ~124 MB successfully)

  short* xb   = (short*)((char*)d_ws + o_xb);
  short* WcT  = (short*)((char*)d_ws + o_wct);
  float* bc   = (float*)((char*)d_ws + o_bc);
  int*   cnt  = (int*)((char*)d_ws + o_cnt);
  int*   offv = (int*)((char*)d_ws + o_off);
  int*   slot = (int*)((char*)d_ws + o_slot);
  int*   perm = (int*)((char*)d_ws + o_perm);
  int*   rows = (int*)((char*)d_ws + o_rows);
  int*   bsum = (int*)((char*)d_ws + o_bsum);
  int*   bpre = (int*)((char*)d_ws + o_bpre);

  hipMemsetAsync(cnt, 0, CNT_B, stream);
  k_prep<<<PREP_NB + HIST_NB, 256, 0, stream>>>(x, xb, ei, cnt, slot);
  k_prep_wc<<<KTOT + 1, 128, 0, stream>>>(W1, b1, W2, WcT, bc);

  k_scan_a<<<SCAN_NB, 256, 0, stream>>>(cnt, bsum);
  k_scan_b<<<1, 256, 0, stream>>>(bsum, bpre);
  k_scan_c<<<SCAN_NB, 256, 0, stream>>>(cnt, bpre, offv);
  k_place2<<<(N_EDGES + 255) / 256, 256, 0, stream>>>(ei, offv, slot, perm, rows);

  k_outF<<<N_NODES / BM, 256, 0, stream>>>(xb, ea, offv, cnt, rows, perm,
                                           WcT, bc, b2, out);
}

// Round 7
// 214.261 us; speedup vs baseline: 1.4344x; 1.4344x over previous
//
#include <hip/hip_runtime.h>
#include <hip/hip_bf16.h>

#define N_NODES 200000
#define N_EDGES 640000
#define D_NODE 128
#define D_EDGE 32
#define HIDDEN 128
#define KTOT 288          // 128 (x) + 128 (Sx) + 32 (Sea)

using bf16x8  = __attribute__((ext_vector_type(8))) short;
using f32x4   = __attribute__((ext_vector_type(4))) float;
using short4v = __attribute__((ext_vector_type(4))) short;

__device__ __forceinline__ short f2b(float f) {
  return __builtin_bit_cast(short, __float2bfloat16(f));
}
__device__ __forceinline__ float b2f(short s) {
  unsigned u = ((unsigned)(unsigned short)s) << 16;
  return __builtin_bit_cast(float, u);
}

// ===========================================================================
// k_prep: one launch, three block ranges
//   [0, 12500)      : AF[:,0:128] = bf16(x)
//   [12500, 15000)  : hist  (slot[e] = atomicAdd(cnt[dst], 1))
//   [15000, 15145)  : WcT = bf16([W2_top ; W1@W2_bot]^T), bc = b1@W2_bot
// ===========================================================================
#define PREP_NB 12500   // N_NODES*16/256
#define HIST_NB 2500    // N_EDGES/256
#define WC_NB   145     // ceil((288*128 + 128)/256)

__global__ __launch_bounds__(256) void k_prep(
    const float* __restrict__ x, short* __restrict__ AF,
    const int* __restrict__ ei, int* cnt, int* slot,
    const float* __restrict__ W1, const float* __restrict__ b1,
    const float* __restrict__ W2, short* __restrict__ WcT,
    float* __restrict__ bc)
{
  const int b = blockIdx.x;
  if (b < PREP_NB) {
    const int i = b * 256 + threadIdx.x;
    const int node = i >> 4;
    const int oct  = (i & 15) << 3;
    const float4 v0 = *(const float4*)&x[(size_t)node * D_NODE + oct];
    const float4 v1 = *(const float4*)&x[(size_t)node * D_NODE + oct + 4];
    bf16x8 o = { f2b(v0.x), f2b(v0.y), f2b(v0.z), f2b(v0.w),
                 f2b(v1.x), f2b(v1.y), f2b(v1.z), f2b(v1.w) };
    *(bf16x8*)&AF[(size_t)node * KTOT + oct] = o;
  } else if (b < PREP_NB + HIST_NB) {
    const int e = (b - PREP_NB) * 256 + threadIdx.x;
    slot[e] = atomicAdd(&cnt[ei[N_EDGES + e]], 1);
  } else {
    const int t = (b - PREP_NB - HIST_NB) * 256 + threadIdx.x;
    if (t < 288 * 128) {
      const int brow = t >> 7, c = t & 127;
      if (brow < 128) {
        WcT[c * KTOT + brow] = f2b(W2[brow * 128 + c]);
      } else {
        const int i = brow - 128;
        float acc = 0.f;
        #pragma unroll 8
        for (int q = 0; q < 128; ++q)
          acc += W1[i * 128 + q] * W2[(128 + q) * 128 + c];
        WcT[c * KTOT + brow] = f2b(acc);
      }
    } else if (t < 288 * 128 + 128) {
      const int c = t - 288 * 128;
      float acc = 0.f;
      #pragma unroll 8
      for (int q = 0; q < 128; ++q)
        acc += b1[q] * W2[(128 + q) * 128 + c];
      bc[c] = acc;
    }
  }
}

// ===========================================================================
// CSR: scan_a (per-1024 block sums) -> scan_c2 (self-computed prefix) -> place
// ===========================================================================
#define SCAN_NB 196  // ceil(200000/1024)

__global__ __launch_bounds__(256) void k_scan_a(const int* __restrict__ cnt,
                                                int* bsum) {
  __shared__ int sh[256];
  const int b = blockIdx.x, t = threadIdx.x;
  const int base = b * 1024 + t * 4;
  int s = 0;
  #pragma unroll
  for (int k = 0; k < 4; ++k) {
    const int idx = base + k;
    s += (idx < N_NODES) ? cnt[idx] : 0;
  }
  sh[t] = s; __syncthreads();
  for (int o = 128; o > 0; o >>= 1) {
    if (t < o) sh[t] += sh[t + o];
    __syncthreads();
  }
  if (t == 0) bsum[b] = sh[0];
}

__global__ __launch_bounds__(256) void k_scan_c2(const int* __restrict__ cnt,
                                                 const int* __restrict__ bsum,
                                                 int* offv) {
  __shared__ int sh[256];
  __shared__ int base_sh;
  const int b = blockIdx.x, t = threadIdx.x;

  // block-prefix base = sum of bsum[0..b)
  sh[t] = (t < SCAN_NB && t < b) ? bsum[t] : 0;
  __syncthreads();
  for (int o = 128; o > 0; o >>= 1) {
    if (t < o) sh[t] += sh[t + o];
    __syncthreads();
  }
  if (t == 0) base_sh = sh[0];
  __syncthreads();

  const int base = b * 1024 + t * 4;
  int v[4], p[4], s = 0;
  #pragma unroll
  for (int k = 0; k < 4; ++k) {
    const int idx = base + k;
    v[k] = (idx < N_NODES) ? cnt[idx] : 0;
    p[k] = s; s += v[k];
  }
  sh[t] = s; __syncthreads();
  const int tot = s;
  for (int o = 1; o < 256; o <<= 1) {
    const int tv = (t >= o) ? sh[t - o] : 0;
    __syncthreads();
    sh[t] += tv;
    __syncthreads();
  }
  const int gb = base_sh + (sh[t] - tot);
  #pragma unroll
  for (int k = 0; k < 4; ++k) {
    const int idx = base + k;
    if (idx < N_NODES) offv[idx] = gb + p[k];
  }
}

// pr[j] = { src_row, edge_id } as one 8B store (1 line vs 2 scattered 4B)
__global__ __launch_bounds__(256) void k_place3(const int* __restrict__ ei,
                                                const int* __restrict__ offv,
                                                const int* __restrict__ slot,
                                                int2* __restrict__ pr) {
  const int e = blockIdx.x * 256 + threadIdx.x;
  if (e < N_EDGES) {
    const int j = offv[ei[N_EDGES + e]] + slot[e];
    int2 v; v.x = ei[e]; v.y = e;
    pr[j] = v;
  }
}

// ===========================================================================
// S aggregation into AF (cols 128:288).  LDS-free, high-occupancy.
//   gtid < 3.2M : AF[n][128+d] = sum over run of AF[pr[j].x][d]   (x part)
//   else        : AF[n][256+q] = sum over run of ea[pr[j].y][q]   (ea part)
// Sx run loop hand-unrolled 2-wide for MLP.
// ===========================================================================
__global__ __launch_bounds__(256) void k_sagg(
    const float* __restrict__ ea, const int* __restrict__ offv,
    const int* __restrict__ cnt, const int2* __restrict__ pr,
    short* __restrict__ AF)
{
  const int gtid = blockIdx.x * 256 + threadIdx.x;
  if (gtid < N_NODES * 16) {
    const int node = gtid >> 4;
    const int oct  = (gtid & 15) << 3;
    const int s0 = offv[node];
    const int s1 = s0 + cnt[node];
    float a[8] = {};
    int j = s0;
    for (; j + 1 < s1; j += 2) {
      const int r0 = pr[j].x;
      const int r1 = pr[j + 1].x;
      const bf16x8 v0 = *(const bf16x8*)&AF[(size_t)r0 * KTOT + oct];
      const bf16x8 v1 = *(const bf16x8*)&AF[(size_t)r1 * KTOT + oct];
      #pragma unroll
      for (int k = 0; k < 8; ++k) a[k] += b2f(v0[k]) + b2f(v1[k]);
    }
    if (j < s1) {
      const bf16x8 v = *(const bf16x8*)&AF[(size_t)pr[j].x * KTOT + oct];
      #pragma unroll
      for (int k = 0; k < 8; ++k) a[k] += b2f(v[k]);
    }
    bf16x8 o;
    #pragma unroll
    for (int k = 0; k < 8; ++k) o[k] = f2b(a[k]);
    *(bf16x8*)&AF[(size_t)node * KTOT + 128 + oct] = o;
  } else {
    const int t2 = gtid - N_NODES * 16;
    const int node = t2 >> 3;
    const int q    = (t2 & 7) << 2;
    if (node >= N_NODES) return;
    const int s0 = offv[node];
    const int s1 = s0 + cnt[node];
    float a0 = 0.f, a1 = 0.f, a2 = 0.f, a3 = 0.f;
    for (int j = s0; j < s1; ++j) {
      const float4 v = *(const float4*)&ea[(size_t)pr[j].y * D_EDGE + q];
      a0 += v.x; a1 += v.y; a2 += v.z; a3 += v.w;
    }
    short4v o = { f2b(a0), f2b(a1), f2b(a2), f2b(a3) };
    *(short4v*)&AF[(size_t)node * KTOT + 256 + q] = o;
  }
}

// ===========================================================================
// Output GEMM: out = AF @ Wc + cnt*bc + b2.
//   BM=64 (grid 3125, exact), K=288 in 3x96 phases, LDS 39.9KB -> 4 blocks/CU.
//   Epilogue via LDS -> coalesced float4 row stores.  (round-5 proven)
// ===========================================================================
#define LDP 104   // 96+8 bf16: 208B rows -> 2-way bank alias only (free)

__global__ __launch_bounds__(256, 4) void k_out2(
    const short* __restrict__ AF, const short* __restrict__ WcT,
    const float* __restrict__ bc, const float* __restrict__ b2,
    const int* __restrict__ cnt, float* __restrict__ out)
{
  __shared__ short smem[64 * LDP + 128 * LDP];   // 39936 B
  short* lA = smem;
  short* lB = smem + 64 * LDP;
  const int tid = threadIdx.x;
  const int n0  = blockIdx.x * 64;

  const int lane = tid & 63;
  const int wid  = tid >> 6;
  const int wm = wid >> 1, wn = wid & 1;          // 2x2 waves, 32x64 out each
  const int lrow = lane & 15;
  const int lk   = (lane >> 4) << 3;

  f32x4 acc[2][4] = {};

  #pragma unroll
  for (int p = 0; p < 3; ++p) {
    for (int i = tid; i < 1536; i += 256) {       // lB: 128 rows x 12 octs
      const int n = i / 12, ck = (i % 12) << 3;
      *(bf16x8*)&lB[n * LDP + ck] = *(const bf16x8*)&WcT[n * KTOT + p * 96 + ck];
    }
    for (int i = tid; i < 768; i += 256) {        // lA: 64 rows x 12 octs
      const int m = i / 12, ck = (i % 12) << 3;
      *(bf16x8*)&lA[m * LDP + ck] = *(const bf16x8*)&AF[(size_t)(n0 + m) * KTOT + p * 96 + ck];
    }
    __syncthreads();
    #pragma unroll
    for (int kt = 0; kt < 3; ++kt) {
      const int ks = kt * 32 + lk;
      bf16x8 af[2], bfr[4];
      #pragma unroll
      for (int i = 0; i < 2; ++i)
        af[i]  = *(const bf16x8*)&lA[(wm * 32 + i * 16 + lrow) * LDP + ks];
      #pragma unroll
      for (int j = 0; j < 4; ++j)
        bfr[j] = *(const bf16x8*)&lB[(wn * 64 + j * 16 + lrow) * LDP + ks];
      #pragma unroll
      for (int i = 0; i < 2; ++i)
        #pragma unroll
        for (int j = 0; j < 4; ++j)
          acc[i][j] = __builtin_amdgcn_mfma_f32_16x16x32_bf16(af[i], bfr[j], acc[i][j], 0, 0, 0);
    }
    __syncthreads();
  }

  // ---- epilogue: acc + cnt*bc + b2 -> LDS f32 [64][128] -> coalesced stores
  float* lf = (float*)smem;                       // 32768 B <= 39936 B
  const int rb = wm * 32 + ((lane >> 4) << 2);
  const int cb = wn * 64 + lrow;
  float bcv[4], b2v[4];
  #pragma unroll
  for (int j = 0; j < 4; ++j) {
    bcv[j] = bc[cb + j * 16];
    b2v[j] = b2[cb + j * 16];
  }
  #pragma unroll
  for (int i = 0; i < 2; ++i) {
    #pragma unroll
    for (int r = 0; r < 4; ++r) {
      const int row = rb + i * 16 + r;
      const float cf = (float)cnt[n0 + row];
      #pragma unroll
      for (int j = 0; j < 4; ++j)
        lf[row * 128 + cb + j * 16] = acc[i][j][r] + cf * bcv[j] + b2v[j];
    }
  }
  __syncthreads();
  #pragma unroll
  for (int u = 0; u < 8; ++u) {
    const int idx = tid + u * 256;                // 2048 float4s
    const int row = idx >> 5, f4 = (idx & 31) << 2;
    *(float4*)&out[(size_t)(n0 + row) * HIDDEN + f4] = *(const float4*)&lf[row * 128 + f4];
  }
}

extern "C" void kernel_launch(void* const* d_in, const int* in_sizes, int n_in,
                              void* d_out, int out_size, void* d_ws, size_t ws_size,
                              hipStream_t stream) {
  const float* x  = (const float*)d_in[0];
  const int*   ei = (const int*)d_in[1];
  const float* ea = (const float*)d_in[2];
  const float* W1 = (const float*)d_in[5];
  const float* b1 = (const float*)d_in[6];
  const float* W2 = (const float*)d_in[7];
  const float* b2 = (const float*)d_in[8];
  float* out = (float*)d_out;

  const size_t AF_B   = (size_t)N_NODES * KTOT * 2;   // 115,200,000
  const size_t WCT_B  = 128 * KTOT * 2;               //      73,728
  const size_t BC_B   = 512;
  const size_t CNT_B  = (size_t)N_NODES * 4;          //     800,000
  const size_t SLOT_B = (size_t)N_EDGES * 4;          //   2,560,000
  const size_t PR_B   = (size_t)N_EDGES * 8;          //   5,120,000

  const size_t o_AF   = 0;
  const size_t o_wct  = o_AF + AF_B;
  const size_t o_bc   = o_wct + WCT_B;
  const size_t o_cnt  = o_bc + BC_B;
  const size_t o_off  = o_cnt + CNT_B;
  const size_t o_slot = o_off + CNT_B;
  const size_t o_pr   = o_slot + SLOT_B;
  const size_t o_bsum = o_pr + PR_B;
  // total ~124.5 MB (round-5's 124.2 MB plan fit)

  short* AF   = (short*)((char*)d_ws + o_AF);
  short* WcT  = (short*)((char*)d_ws + o_wct);
  float* bc   = (float*)((char*)d_ws + o_bc);
  int*   cnt  = (int*)((char*)d_ws + o_cnt);
  int*   offv = (int*)((char*)d_ws + o_off);
  int*   slot = (int*)((char*)d_ws + o_slot);
  int2*  pr   = (int2*)((char*)d_ws + o_pr);
  int*   bsum = (int*)((char*)d_ws + o_bsum);

  hipMemsetAsync(cnt, 0, CNT_B, stream);
  k_prep<<<PREP_NB + HIST_NB + WC_NB, 256, 0, stream>>>(
      x, AF, ei, cnt, slot, W1, b1, W2, WcT, bc);

  k_scan_a <<<SCAN_NB, 256, 0, stream>>>(cnt, bsum);
  k_scan_c2<<<SCAN_NB, 256, 0, stream>>>(cnt, bsum, offv);
  k_place3 <<<(N_EDGES + 255) / 256, 256, 0, stream>>>(ei, offv, slot, pr);

  k_sagg<<<(N_NODES * 24 + 255) / 256, 256, 0, stream>>>(ea, offv, cnt, pr, AF);
  k_out2<<<N_NODES / 64, 256, 0, stream>>>(AF, WcT, bc, b2, cnt, out);
}